// Round 4
// baseline (293.646 us; speedup 1.0000x reference)
//
#include <hip/hip_runtime.h>

#define IRE (1.0f / 400.0f)

constexpr int W  = 512;
constexpr int H  = 512;
constexpr int NB = 64;
constexpr int TR = 32;                  // rows per block tile
constexpr int TILES = H / TR;           // 16
constexpr int NBLK  = NB * TILES;       // 1024 blocks = 4/CU
constexpr int NSLOT = 5;                // ring: 5 slots x 4 arrays x 512 f32 = 40960 B
                                        // 4 blocks x 40960 = 160 KiB exactly

// Round-4 change: per-block ROW-PHASE ROTATION. Every prior variant marched rows in
// lockstep (all blocks at the same row-phase s, tiles 64KB-aligned, arrays 1MB-aligned),
// so instantaneous demand concentrated on the same slice of the DRAM/L2 channel
// interleave -> ~2.5 TB/s service cap invariant to kernel structure. Rotating each
// block's starting row by sigma = (blk*13)&31 spreads in-flight addresses across the
// full 64 KB period. Machinery (ring, counted vmcnt, single barrier/iter) unchanged.

__device__ __forceinline__ void residuals3(
    float um, float vm, float ul, float vl, float ur, float vr,
    float ub, float vb, float ut, float vt,
    float& mass, float& momu, float& momv)
{
    float dudx = (ur - ul) * 0.5f;
    float dvdy = (vt - vb) * 0.5f;
    float ru = ur + um, lu = ul + um, tu_ = ut + um, bu = ub + um;
    float rv = vr + vm, lv = vl + vm, tv_ = vt + vm, bv = vb + vm;
    float du2dx = 0.25f * (ru * ru - lu * lu);
    float duvdy = 0.25f * (tu_ * tv_ - bu * bv);
    float dv2dy = 0.25f * (tv_ * tv_ - bv * bv);
    float dvudx = 0.25f * (rv * ru - lv * lu);
    float dudx2 = ur - 2.0f * um + ul;
    float dudy2 = ut - 2.0f * um + ub;
    float dvdx2 = vr - 2.0f * vm + vl;
    float dvdy2 = vt - 2.0f * vm + vb;
    mass = dudx + dvdy;
    momu = du2dx + duvdy - (dudx2 + dudy2) * IRE;
    momv = dvudx + dv2dy - (dvdx2 + dvdy2) * IRE;
}

__global__ __launch_bounds__(256, 4) void loss_main(
    const float* __restrict__ pred, const float* __restrict__ trut,
    double* __restrict__ partial)
{
    __shared__ __align__(16) float ring[NSLOT * 4 * W];   // 40960 B

    const int tid  = (int)threadIdx.x;
    const int lane = tid & 63;
    const int wv   = tid >> 6;           // wave stages array wv (0:tu 1:tv 2:pu 3:pv)
    const int blk  = (int)blockIdx.x;
    const int tile = blk % TILES;
    const int b    = blk / TILES;
    const int r0   = tile * TR;
    const int sig  = (blk * 13) & 31;    // row-phase rotation, uniform over [0,32)

    const size_t CH = (size_t)H * W;
    const float* gbase = (wv < 2 ? trut : pred) + (size_t)b * 2 * CH + (size_t)(wv & 1) * CH;

    // async global->LDS: wave-uniform LDS dest (+lane*16 by HW), per-lane global src
    auto stage_row = [&](int row, int slot) {
        row = row < 0 ? 0 : (row > H - 1 ? H - 1 : row);
        const float* src = gbase + (size_t)row * W + lane * 4;
        float* dst = &ring[slot * (4 * W) + wv * W];
        __builtin_amdgcn_global_load_lds(
            (const __attribute__((address_space(1))) void*)src,
            (__attribute__((address_space(3))) void*)dst, 16, 0, 0);
        __builtin_amdgcn_global_load_lds(
            (const __attribute__((address_space(1))) void*)(src + 256),
            (__attribute__((address_space(3))) void*)(dst + 256), 16, 0, 0);
    };

    const int j0  = tid * 2;                          // this thread's 2 columns
    const int jm1 = (j0 == 0) ? 0 : j0 - 1;           // clamped (value masked anyway)
    const int jp2 = (j0 + 2 > W - 1) ? W - 1 : j0 + 2;

    float accMass = 0.0f, accMom = 0.0f, accL1 = 0.0f;

    // register window: rows r-1 (top), r (mid, + lf/rt), r+1 (bot, LDS-read per iter)
    float2 topc[4], midc[4], botc[4];
    float  midl[4], midr[4], botl[4], botr[4];

    int qb = 0;   // ring base slot for the next run's prologue

    // process output rows rs .. rs+n-1 (n >= 1) with the round-3 protocol
    auto runRows = [&](int rs, int n) {
        const int s0 = qb;
        const int s1 = (qb + 1) % NSLOT;
        const int s2 = (qb + 2) % NSLOT;
        const int s3 = (qb + 3) % NSLOT;
        const int s4 = (qb + 4) % NSLOT;
        // prologue: stage rows rs-1..rs+2 (8 VMEM / wave outstanding)
        stage_row(rs - 1, s0);
        stage_row(rs,     s1);
        stage_row(rs + 1, s2);
        stage_row(rs + 2, s3);
        asm volatile("s_waitcnt vmcnt(4)\n\ts_barrier" ::: "memory");   // rows rs-1, rs landed
        #pragma unroll
        for (int a = 0; a < 4; ++a) {
            const float* p0 = &ring[s0 * (4 * W) + a * W];
            const float* p1 = &ring[s1 * (4 * W) + a * W];
            topc[a] = *(const float2*)(p0 + j0);
            midc[a] = *(const float2*)(p1 + j0);
            midl[a] = p1[jm1];
            midr[a] = p1[jp2];
        }

        int sBot = s2, sStage = s4;
        #pragma unroll 4
        for (int s = 0; s < n; ++s) {
            const int r = rs + s;
            if (s < n - 2) {
                stage_row(r + 3, sStage);
                asm volatile("s_waitcnt vmcnt(4) lgkmcnt(0)\n\ts_barrier" ::: "memory");
            } else if (s == n - 2) {
                asm volatile("s_waitcnt vmcnt(2) lgkmcnt(0)\n\ts_barrier" ::: "memory");
            } else {
                asm volatile("s_waitcnt vmcnt(0) lgkmcnt(0)\n\ts_barrier" ::: "memory");
            }

            // single LDS visit per row: read row r+1 (bot) only
            const float* bp = &ring[sBot * (4 * W)];
            #pragma unroll
            for (int a = 0; a < 4; ++a) {
                botc[a] = *(const float2*)(bp + a * W + j0);   // ds_read_b64, 2-way (free)
                botl[a] = bp[a * W + jm1];
                botr[a] = bp[a * W + jp2];
            }

            // L1 on mid row (each row owned by exactly one block-iter across both runs)
            accL1 += fabsf(midc[2].x - midc[0].x) + fabsf(midc[2].y - midc[0].y)
                   + fabsf(midc[3].x - midc[1].x) + fabsf(midc[3].y - midc[1].y);

            if (r >= 1 && r <= H - 2) {                   // wave-uniform row mask
                float mT, uT, vT, mP, uP, vP;
                // point j0: ul/ur = prev/next ROW, ub/ut = left/right COL (matches ref)
                residuals3(midc[0].x, midc[1].x, topc[0].x, topc[1].x, botc[0].x, botc[1].x,
                           midl[0],   midl[1],   midc[0].y, midc[1].y, mT, uT, vT);
                residuals3(midc[2].x, midc[3].x, topc[2].x, topc[3].x, botc[2].x, botc[3].x,
                           midl[2],   midl[3],   midc[2].y, midc[3].y, mP, uP, vP);
                if (j0 >= 1) {                            // only thread 0 masked
                    accMass += fabsf(mT - mP);
                    accMom  += fabsf(uT - uP) + fabsf(vT - vP);
                }
                // point j0+1
                residuals3(midc[0].y, midc[1].y, topc[0].y, topc[1].y, botc[0].y, botc[1].y,
                           midc[0].x, midc[1].x, midr[0],   midr[1],   mT, uT, vT);
                residuals3(midc[2].y, midc[3].y, topc[2].y, topc[3].y, botc[2].y, botc[3].y,
                           midc[2].x, midc[3].x, midr[2],   midr[3],   mP, uP, vP);
                if (j0 + 1 <= W - 2) {                    // only thread 255 masked
                    accMass += fabsf(mT - mP);
                    accMom  += fabsf(uT - uP) + fabsf(vT - vP);
                }
            }

            // rotate window (renamed away by unroll)
            #pragma unroll
            for (int a = 0; a < 4; ++a) {
                topc[a] = midc[a];
                midc[a] = botc[a];
                midl[a] = botl[a];
                midr[a] = botr[a];
            }
            sBot   = (sBot   == NSLOT - 1) ? 0 : sBot + 1;
            sStage = (sStage == NSLOT - 1) ? 0 : sStage + 1;
        }

        // advance ring base by the number of stages issued this run
        const int st = 4 + (n >= 3 ? n - 2 : 0);
        qb = (qb + st) % NSLOT;
        // vmcnt already 0 (last iter). Retire all ds_reads machine-wide before the
        // next run's prologue re-stages slots that were just read.
        asm volatile("s_waitcnt lgkmcnt(0)\n\ts_barrier" ::: "memory");
    };

    runRows(r0 + sig, TR - sig);          // output rows r0+sig .. r0+31
    if (sig > 0) runRows(r0, sig);        // output rows r0 .. r0+sig-1

    float res = 5.0f * accMass + 25.0f * accMom;
    float l1  = accL1;
    #pragma unroll
    for (int off = 32; off > 0; off >>= 1) {
        res += __shfl_down(res, off);
        l1  += __shfl_down(l1, off);
    }
    __syncthreads();                                  // loop done; safe to reuse ring LDS
    double* sred = (double*)ring;
    if (lane == 0) { sred[wv] = (double)res; sred[4 + wv] = (double)l1; }
    __syncthreads();
    if (tid == 0) {
        partial[(size_t)blk * 2 + 0] = sred[0] + sred[1] + sred[2] + sred[3];
        partial[(size_t)blk * 2 + 1] = sred[4] + sred[5] + sred[6] + sred[7];
    }
}

__global__ __launch_bounds__(256) void loss_final(
    const double* __restrict__ partial, float* __restrict__ out)
{
    __shared__ double sres[4], sl1[4];
    const int t = (int)threadIdx.x;
    double res = 0.0, l1 = 0.0;
    for (int i = t; i < NBLK; i += 256) {
        res += partial[(size_t)i * 2 + 0];
        l1  += partial[(size_t)i * 2 + 1];
    }
    #pragma unroll
    for (int off = 32; off > 0; off >>= 1) {
        res += __shfl_down(res, off);
        l1  += __shfl_down(l1, off);
    }
    const int wave = t >> 6;
    if ((t & 63) == 0) { sres[wave] = res; sl1[wave] = l1; }
    __syncthreads();
    if (t == 0) {
        res = sres[0] + sres[1] + sres[2] + sres[3];
        l1  = sl1[0] + sl1[1] + sl1[2] + sl1[3];
        const double nRes = 64.0 * 510.0 * 510.0;
        const double nL1  = 64.0 * 2.0 * 512.0 * 512.0;
        out[0] = (float)((res / nRes + l1 / nL1) / 3.0);
    }
}

extern "C" void kernel_launch(void* const* d_in, const int* in_sizes, int n_in,
                              void* d_out, int out_size, void* d_ws, size_t ws_size,
                              hipStream_t stream)
{
    const float* pred = (const float*)d_in[0];
    const float* trut = (const float*)d_in[1];
    double* partial = (double*)d_ws;   // 1024*2 doubles = 16 KB, written before read
    loss_main<<<NBLK, 256, 0, stream>>>(pred, trut, partial);
    loss_final<<<1, 256, 0, stream>>>(partial, (float*)d_out);
}

// Round 5
// 282.983 us; speedup vs baseline: 1.0377x; 1.0377x over previous
//
#include <hip/hip_runtime.h>

#define IRE (1.0f / 400.0f)

constexpr int W  = 512;
constexpr int H  = 512;
constexpr int NB = 64;
constexpr int TR = 32;                  // rows per block tile
constexpr int TILES = H / TR;           // 16
constexpr int NBLK  = NB * TILES;       // 1024 blocks
constexpr int TPB   = 512;              // 8 waves/block  -> 32 waves/CU at 4 blocks/CU
constexpr int NSLOT = 4;                // ring: 4 slots x 4 arrays x 512 f32 = 32768 B
                                        // 4 blocks x 32 KiB = 128 KiB -> guaranteed residency

// ROUND-5 EXPERIMENT: concurrency. All six prior variants ran 12-16 waves/CU (and the
// 40960-B ring resided only 3 blocks/CU => 25% straggler tail). This version doubles
// resident waves (512-thr blocks, 8 waves each, 1 global_load_lds per wave per iter)
// and shrinks the ring to 32 KiB so 4 blocks/CU always fit. Pipeline protocol is
// otherwise identical to round 3 (lookahead-2, counted vmcnt, 1 barrier/iter).
// Slot reuse: slot of row x re-staged at iter x+1 was last ds_read at iter x-1;
// the intervening barrier's lgkmcnt(0) retires those reads. An extra barrier after
// the prologue register-init protects slot 0's first reuse.

__device__ __forceinline__ void residuals3(
    float um, float vm, float ul, float vl, float ur, float vr,
    float ub, float vb, float ut, float vt,
    float& mass, float& momu, float& momv)
{
    float dudx = (ur - ul) * 0.5f;
    float dvdy = (vt - vb) * 0.5f;
    float ru = ur + um, lu = ul + um, tu_ = ut + um, bu = ub + um;
    float rv = vr + vm, lv = vl + vm, tv_ = vt + vm, bv = vb + vm;
    float du2dx = 0.25f * (ru * ru - lu * lu);
    float duvdy = 0.25f * (tu_ * tv_ - bu * bv);
    float dv2dy = 0.25f * (tv_ * tv_ - bv * bv);
    float dvudx = 0.25f * (rv * ru - lv * lu);
    float dudx2 = ur - 2.0f * um + ul;
    float dudy2 = ut - 2.0f * um + ub;
    float dvdx2 = vr - 2.0f * vm + vl;
    float dvdy2 = vt - 2.0f * vm + vb;
    mass = dudx + dvdy;
    momu = du2dx + duvdy - (dudx2 + dudy2) * IRE;
    momv = dvudx + dv2dy - (dvdx2 + dvdy2) * IRE;
}

__global__ __launch_bounds__(TPB, 8) void loss_main(
    const float* __restrict__ pred, const float* __restrict__ trut,
    double* __restrict__ partial)
{
    __shared__ __align__(16) float ring[NSLOT * 4 * W];   // 32768 B

    const int tid  = (int)threadIdx.x;
    const int lane = tid & 63;
    const int wv   = tid >> 6;           // 8 waves: wave wv stages (array wv>>1, half wv&1)
    const int arr  = wv >> 1;            // 0:tu 1:tv 2:pu 3:pv
    const int half = wv & 1;             // which 256-col half of the row
    const int blk  = (int)blockIdx.x;
    const int tile = blk % TILES;
    const int b    = blk / TILES;
    const int r0   = tile * TR;

    const size_t CH = (size_t)H * W;
    const float* gbase = (arr < 2 ? trut : pred) + (size_t)b * 2 * CH + (size_t)(arr & 1) * CH;

    // one wave = one 1 KiB global_load_lds per row (wave-uniform LDS dst, per-lane src)
    auto stage_row = [&](int row, int slot) {
        row = row < 0 ? 0 : (row > H - 1 ? H - 1 : row);
        const float* src = gbase + (size_t)row * W + half * 256 + lane * 4;
        float* dst = &ring[slot * (4 * W) + arr * W + half * 256];
        __builtin_amdgcn_global_load_lds(
            (const __attribute__((address_space(1))) void*)src,
            (__attribute__((address_space(3))) void*)dst, 16, 0, 0);
    };

    // prologue: rows r0-1..r0+2 -> slots 0..3 (4 outstanding / wave)
    stage_row(r0 - 1, 0);
    stage_row(r0,     1);
    stage_row(r0 + 1, 2);
    stage_row(r0 + 2, 3);

    const int j0  = tid;                              // this thread's single column
    const int jm1 = (j0 == 0) ? 0 : j0 - 1;           // clamped (value masked anyway)
    const int jp1 = (j0 == W - 1) ? W - 1 : j0 + 1;

    float accMass = 0.0f, accMom = 0.0f, accL1 = 0.0f;

    // register window: top center, mid l/c/r, per-iter bottom l/c/r (4 arrays each)
    float tc[4], ml[4], mc[4], mr[4], bl[4], bc[4], br[4];

    // publish rows r0-1, r0 (2 newest stages stay in flight)
    asm volatile("s_waitcnt vmcnt(2)\n\ts_barrier" ::: "memory");
    #pragma unroll
    for (int a = 0; a < 4; ++a) {
        const float* p0 = &ring[0 * (4 * W) + a * W];
        const float* p1 = &ring[1 * (4 * W) + a * W];
        tc[a] = p0[j0];
        ml[a] = p1[jm1];
        mc[a] = p1[j0];
        mr[a] = p1[jp1];
    }
    // retire all prologue reads before iter-0's stage reuses slot 0
    asm volatile("s_waitcnt lgkmcnt(0)\n\ts_barrier" ::: "memory");

    int sBot = 2, sStage = 0;            // slots of row r+1 (read) and row r+3 (stage)
    #pragma unroll 4
    for (int s = 0; s < TR; ++s) {
        const int r = r0 + s;
        if (s < TR - 2) {
            stage_row(r + 3, sStage);
            asm volatile("s_waitcnt vmcnt(2) lgkmcnt(0)\n\ts_barrier" ::: "memory");
        } else if (s == TR - 2) {
            asm volatile("s_waitcnt vmcnt(1) lgkmcnt(0)\n\ts_barrier" ::: "memory");
        } else {
            asm volatile("s_waitcnt vmcnt(0) lgkmcnt(0)\n\ts_barrier" ::: "memory");
        }

        // single LDS visit per row: read row r+1 (bot) only, 3 stride-1 b32 per array
        const float* bp = &ring[sBot * (4 * W)];
        #pragma unroll
        for (int a = 0; a < 4; ++a) {
            bl[a] = bp[a * W + jm1];
            bc[a] = bp[a * W + j0];
            br[a] = bp[a * W + jp1];
        }

        // L1 on mid row (each row/col/channel owned by exactly one thread-iter)
        accL1 += fabsf(mc[2] - mc[0]) + fabsf(mc[3] - mc[1]);

        if (r >= 1 && r <= H - 2) {                   // wave-uniform row mask
            float mT, uT, vT, mP, uP, vP;
            // ul/ur = prev/next ROW, ub/ut = left/right COL (matches reference)
            residuals3(mc[0], mc[1], tc[0], tc[1], bc[0], bc[1],
                       ml[0], ml[1], mr[0], mr[1], mT, uT, vT);
            residuals3(mc[2], mc[3], tc[2], tc[3], bc[2], bc[3],
                       ml[2], ml[3], mr[2], mr[3], mP, uP, vP);
            if (j0 >= 1 && j0 <= W - 2) {             // only threads 0 and 511 masked
                accMass += fabsf(mT - mP);
                accMom  += fabsf(uT - uP) + fabsf(vT - vP);
            }
        }

        // rotate window (renamed away by unroll)
        #pragma unroll
        for (int a = 0; a < 4; ++a) {
            tc[a] = mc[a];
            ml[a] = bl[a];
            mc[a] = bc[a];
            mr[a] = br[a];
        }
        sBot   = (sBot   + 1) & 3;
        sStage = (sStage + 1) & 3;
    }

    float res = 5.0f * accMass + 25.0f * accMom;
    float l1  = accL1;
    #pragma unroll
    for (int off = 32; off > 0; off >>= 1) {
        res += __shfl_down(res, off);
        l1  += __shfl_down(l1, off);
    }
    __syncthreads();                                  // loop done; safe to reuse ring LDS
    double* sred = (double*)ring;
    if (lane == 0) { sred[wv] = (double)res; sred[8 + wv] = (double)l1; }
    __syncthreads();
    if (tid == 0) {
        double resS = 0.0, l1S = 0.0;
        #pragma unroll
        for (int i = 0; i < 8; ++i) { resS += sred[i]; l1S += sred[8 + i]; }
        partial[(size_t)blk * 2 + 0] = resS;
        partial[(size_t)blk * 2 + 1] = l1S;
    }
}

__global__ __launch_bounds__(256) void loss_final(
    const double* __restrict__ partial, float* __restrict__ out)
{
    __shared__ double sres[4], sl1[4];
    const int t = (int)threadIdx.x;
    double res = 0.0, l1 = 0.0;
    for (int i = t; i < NBLK; i += 256) {
        res += partial[(size_t)i * 2 + 0];
        l1  += partial[(size_t)i * 2 + 1];
    }
    #pragma unroll
    for (int off = 32; off > 0; off >>= 1) {
        res += __shfl_down(res, off);
        l1  += __shfl_down(l1, off);
    }
    const int wave = t >> 6;
    if ((t & 63) == 0) { sres[wave] = res; sl1[wave] = l1; }
    __syncthreads();
    if (t == 0) {
        res = sres[0] + sres[1] + sres[2] + sres[3];
        l1  = sl1[0] + sl1[1] + sl1[2] + sl1[3];
        const double nRes = 64.0 * 510.0 * 510.0;
        const double nL1  = 64.0 * 2.0 * 512.0 * 512.0;
        out[0] = (float)((res / nRes + l1 / nL1) / 3.0);
    }
}

extern "C" void kernel_launch(void* const* d_in, const int* in_sizes, int n_in,
                              void* d_out, int out_size, void* d_ws, size_t ws_size,
                              hipStream_t stream)
{
    const float* pred = (const float*)d_in[0];
    const float* trut = (const float*)d_in[1];
    double* partial = (double*)d_ws;   // 1024*2 doubles = 16 KB, written before read
    loss_main<<<NBLK, TPB, 0, stream>>>(pred, trut, partial);
    loss_final<<<1, 256, 0, stream>>>(partial, (float*)d_out);
}